// Round 2
// baseline (2318.506 us; speedup 1.0000x reference)
//
#include <hip/hip_runtime.h>
#include <hip/hip_bf16.h>

// Problem constants
#define B_  64
#define N_  16384
#define S_  64      // NUM_PATCHES
#define K_  32      // PATCH_POINTS
#define C1_ 64
#define C2_ 128
#define C3_ 384
#define R_  (B_*S_*K_)   // 131072 rows
#define BN_EPS_ 1e-5f

// ws layout (float offsets)
#define PATCH_OFF 0
#define CENT_OFF  (R_*3)                      // 393216
#define NB1_ 512
#define P1_OFF    (CENT_OFF + B_*S_*3)        // 405504
#define SC1_OFF   (P1_OFF + NB1_*C1_*2)       // 471040
#define NB2_ 1024
#define P2_OFF    (SC1_OFF + 2*C1_)           // 471168
#define SC2_OFF   (P2_OFF + NB2_*C2_*2)       // 733312
// total ~733568 floats (~2.9 MB)

// ---------------------------------------------------------------------------
// FPS: one block (1024 threads) per batch. 16 points/thread in registers.
// Distance arithmetic replicates XLA-CPU contraction: fma(dz,dz,fma(dy,dy,dx*dx)).
// ---------------------------------------------------------------------------
__global__ __launch_bounds__(1024) void fps_kernel(const float* __restrict__ x,
        float* __restrict__ centers, float* __restrict__ outCent) {
  int b = blockIdx.x;
  int t = threadIdx.x;
  const float* xb = x + (size_t)b * N_ * 3;
  float px[16], py[16], pz[16], dist[16];
#pragma unroll
  for (int j = 0; j < 16; ++j) {
    int n = j * 1024 + t;
    px[j] = xb[n*3+0]; py[j] = xb[n*3+1]; pz[j] = xb[n*3+2];
    dist[j] = 1e10f;
  }
  __shared__ float cb[3];
  __shared__ float wd[16]; __shared__ int wi[16];
  __shared__ float wx[16], wy[16], wz[16];
  if (t == 0) { cb[0] = px[0]; cb[1] = py[0]; cb[2] = pz[0]; }
  int lane = t & 63, wv = t >> 6;
  for (int s = 0; s < S_; ++s) {
    __syncthreads();
    float cx = cb[0], cy = cb[1], cz = cb[2];
    if (t == 0) {
      int task = b * S_ + s;
      centers[task*3+0] = cx; centers[task*3+1] = cy; centers[task*3+2] = cz;
      outCent[task*3+0] = cx; outCent[task*3+1] = cy; outCent[task*3+2] = cz;
    }
    float bd = -1.0f; int bn = 0; float bx = 0.f, by = 0.f, bz = 0.f;
#pragma unroll
    for (int j = 0; j < 16; ++j) {
      float dx = px[j]-cx, dy = py[j]-cy, dz = pz[j]-cz;
      float d = __builtin_fmaf(dz, dz, __builtin_fmaf(dy, dy, dx*dx));
      float dm = fminf(dist[j], d);
      dist[j] = dm;
      int n = j*1024 + t;
      if (dm > bd) { bd = dm; bn = n; bx = px[j]; by = py[j]; bz = pz[j]; }
    }
#pragma unroll
    for (int m = 1; m < 64; m <<= 1) {
      float od = __shfl_xor(bd, m, 64); int on = __shfl_xor(bn, m, 64);
      float ox = __shfl_xor(bx, m, 64), oy = __shfl_xor(by, m, 64), oz = __shfl_xor(bz, m, 64);
      if (od > bd || (od == bd && on < bn)) { bd = od; bn = on; bx = ox; by = oy; bz = oz; }
    }
    if (lane == 0) { wd[wv] = bd; wi[wv] = bn; wx[wv] = bx; wy[wv] = by; wz[wv] = bz; }
    __syncthreads();
    if (t < 16) {
      bd = wd[t]; bn = wi[t]; bx = wx[t]; by = wy[t]; bz = wz[t];
#pragma unroll
      for (int m = 1; m < 16; m <<= 1) {
        float od = __shfl_xor(bd, m, 64); int on = __shfl_xor(bn, m, 64);
        float ox = __shfl_xor(bx, m, 64), oy = __shfl_xor(by, m, 64), oz = __shfl_xor(bz, m, 64);
        if (od > bd || (od == bd && on < bn)) { bd = od; bn = on; bx = ox; by = oy; bz = oz; }
      }
      if (t == 0) { cb[0] = bx; cb[1] = by; cb[2] = bz; }
    }
  }
}

// ---------------------------------------------------------------------------
// query_ball: one wave per (b,s). Per-lane top-32 (static-indexed registers),
// then 32 rounds of wave-wide lexicographic argmin. Writes centered patches.
// Distance replicates XLA: Bn=fma chain, dt=fma chain, d=fma(-2,dt,A+Bn).
// ---------------------------------------------------------------------------
__global__ __launch_bounds__(256) void qb_kernel(const float* __restrict__ x,
        const float* __restrict__ centers, float* __restrict__ patches) {
  int t = threadIdx.x;
  int lane = t & 63;
  int task = blockIdx.x * 4 + (t >> 6);
  int b = task >> 6;
  const float* xb = x + (size_t)b * N_ * 3;
  float cx = centers[task*3+0], cy = centers[task*3+1], cz = centers[task*3+2];
  float d32[32]; int i32[32];
#pragma unroll
  for (int j = 0; j < 32; ++j) { d32[j] = 3e38f; i32[j] = 0x7fffffff; }
  float maxd = 3e38f; int maxi = 0x7fffffff;
  float A = __builtin_fmaf(cz, cz, __builtin_fmaf(cy, cy, cx*cx));
  for (int jj = 0; jj < 256; ++jj) {
    int n = jj * 64 + lane;
    float qx = xb[n*3+0], qy = xb[n*3+1], qz = xb[n*3+2];
    float Bn = __builtin_fmaf(qz, qz, __builtin_fmaf(qy, qy, qx*qx));
    float dt = __builtin_fmaf(cz, qz, __builtin_fmaf(cy, qy, cx*qx));
    float d  = __builtin_fmaf(-2.0f, dt, A + Bn);
    if (d < maxd || (d == maxd && n < maxi)) {
      bool done = false;
#pragma unroll
      for (int j = 0; j < 32; ++j) {
        if (!done && d32[j] == maxd && i32[j] == maxi) { d32[j] = d; i32[j] = n; done = true; }
      }
      maxd = d32[0]; maxi = i32[0];
#pragma unroll
      for (int j = 1; j < 32; ++j) {
        if (d32[j] > maxd || (d32[j] == maxd && i32[j] > maxi)) { maxd = d32[j]; maxi = i32[j]; }
      }
    }
  }
  int keep = 0;
  for (int r = 0; r < 32; ++r) {
    float md = d32[0]; int mi = i32[0];
#pragma unroll
    for (int j = 1; j < 32; ++j) {
      if (d32[j] < md || (d32[j] == md && i32[j] < mi)) { md = d32[j]; mi = i32[j]; }
    }
#pragma unroll
    for (int m = 1; m < 64; m <<= 1) {
      float od = __shfl_xor(md, m, 64); int oi = __shfl_xor(mi, m, 64);
      if (od < md || (od == md && oi < mi)) { md = od; mi = oi; }
    }
    if (lane == r) keep = mi;
#pragma unroll
    for (int j = 0; j < 32; ++j) if (i32[j] == mi) d32[j] = 3e38f;
  }
  if (lane < 32) {
    int n = keep;
    float qx = xb[n*3+0], qy = xb[n*3+1], qz = xb[n*3+2];
    size_t row = (size_t)task * K_ + lane;
    patches[row*3+0] = qx - cx;
    patches[row*3+1] = qy - cy;
    patches[row*3+2] = qz - cz;
  }
}

// ---------------------------------------------------------------------------
// stats1: per-channel sum / sumsq of h1 = patches@W1^T + b1 (no h1 store)
// ---------------------------------------------------------------------------
__global__ __launch_bounds__(256) void stats1_kernel(const float* __restrict__ patches,
        const float* __restrict__ W1, const float* __restrict__ b1,
        float* __restrict__ part) {
  int t = threadIdx.x;
  int o = t & 63, rg = t >> 6;
  float w0 = W1[o*3+0], w1 = W1[o*3+1], w2 = W1[o*3+2], bb = b1[o];
  int r0 = blockIdx.x * 256 + rg * 64;
  float s1 = 0.f, s2 = 0.f;
  for (int i = 0; i < 64; ++i) {
    const float* p = patches + (size_t)(r0 + i) * 3;
    float h = p[0]*w0 + p[1]*w1 + p[2]*w2 + bb;
    s1 += h; s2 += h*h;
  }
  __shared__ float red[4][64][2];
  red[rg][o][0] = s1; red[rg][o][1] = s2;
  __syncthreads();
  if (t < 64) {
    float a = red[0][t][0] + red[1][t][0] + red[2][t][0] + red[3][t][0];
    float c = red[0][t][1] + red[1][t][1] + red[2][t][1] + red[3][t][1];
    part[blockIdx.x*128 + t*2 + 0] = a;
    part[blockIdx.x*128 + t*2 + 1] = c;
  }
}

// ---------------------------------------------------------------------------
// finalize: deterministic sum of partials -> scale/shift (BN affine form)
// ---------------------------------------------------------------------------
__global__ void finalize_kernel(const float* __restrict__ part, int nblk, int nch,
        const float* __restrict__ g, const float* __restrict__ be,
        float* __restrict__ scale, float* __restrict__ shift) {
  int o = threadIdx.x;
  if (o >= nch) return;
  double s1 = 0.0, s2 = 0.0;
  for (int i = 0; i < nblk; ++i) {
    s1 += (double)part[i*nch*2 + o*2 + 0];
    s2 += (double)part[i*nch*2 + o*2 + 1];
  }
  float m   = (float)(s1 / (double)R_);
  float eh2 = (float)(s2 / (double)R_);
  float v = eh2 - m*m;
  float rs = rsqrtf(v + BN_EPS_);
  float sc = g[o] * rs;
  scale[o] = sc;
  shift[o] = be[o] - m*sc;
}

// ---------------------------------------------------------------------------
// stats2: recompute a1 tile (LDS), h2 = a1@W2^T + b2, per-channel sum/sumsq
// ---------------------------------------------------------------------------
__global__ __launch_bounds__(256) void stats2_kernel(const float* __restrict__ patches,
        const float* __restrict__ W1, const float* __restrict__ b1,
        const float* __restrict__ sc1, const float* __restrict__ sh1,
        const float* __restrict__ W2, const float* __restrict__ b2,
        float* __restrict__ part) {
  __shared__ float a1L[128][68];
  __shared__ float red[2][128][2];
  int t = threadIdx.x;
  int r0 = blockIdx.x * 128;
  {
    int r = t & 127, oh = t >> 7;
    const float* p = patches + (size_t)(r0 + r) * 3;
    float p0 = p[0], p1 = p[1], p2 = p[2];
#pragma unroll
    for (int j = 0; j < 32; ++j) {
      int o = oh*32 + j;
      float h = p0*W1[o*3] + p1*W1[o*3+1] + p2*W1[o*3+2] + b1[o];
      a1L[r][o] = fmaxf(h*sc1[o] + sh1[o], 0.f);
    }
  }
  __syncthreads();
  int o = t & 127, rg = t >> 7;
  float4 wreg[16];
  const float4* w2r = (const float4*)(W2 + o*64);
#pragma unroll
  for (int c = 0; c < 16; ++c) wreg[c] = w2r[c];
  float bb = b2[o];
  float s1 = 0.f, s2 = 0.f;
  for (int i = 0; i < 64; ++i) {
    int r = rg*64 + i;
    float acc = bb;
    const float4* a4 = (const float4*)(&a1L[r][0]);
#pragma unroll
    for (int c = 0; c < 16; ++c) {
      float4 a = a4[c];
      acc += a.x*wreg[c].x; acc += a.y*wreg[c].y;
      acc += a.z*wreg[c].z; acc += a.w*wreg[c].w;
    }
    s1 += acc; s2 += acc*acc;
  }
  red[rg][o][0] = s1; red[rg][o][1] = s2;
  __syncthreads();
  if (t < 128) {
    part[blockIdx.x*256 + t*2 + 0] = red[0][t][0] + red[1][t][0];
    part[blockIdx.x*256 + t*2 + 1] = red[0][t][1] + red[1][t][1];
  }
}

// ---------------------------------------------------------------------------
// embed: per (b,s): patches -> a1 -> a2 (LDS) -> layer3 (LDS-staged swizzled
// W3 tiles, 4e x 2k register tiles) -> max over K -> out. b3 added after max.
// ---------------------------------------------------------------------------
__global__ __launch_bounds__(256) void embed_kernel(const float* __restrict__ patches,
        const float* __restrict__ W1, const float* __restrict__ b1,
        const float* __restrict__ sc1, const float* __restrict__ sh1,
        const float* __restrict__ W2, const float* __restrict__ b2,
        const float* __restrict__ sc2, const float* __restrict__ sh2,
        const float* __restrict__ W3, const float* __restrict__ b3,
        float* __restrict__ out) {
  __shared__ float a1L[32][68];     // 8704 B
  __shared__ float a2L[32][132];    // 16896 B
  __shared__ float wL[8192];        // 32 KB: W2 (swz) for P2, W3 tile (swz) for P3
  __shared__ float PM[16][64];      // 4 KB partial-max
  int t = threadIdx.x;
  int task = blockIdx.x;

  // P1: a1 = relu(bn1(patches@W1^T + b1))
  {
    int k = t & 31, og = t >> 5;
    const float* p = patches + ((size_t)task*K_ + k)*3;
    float p0 = p[0], p1 = p[1], p2 = p[2];
#pragma unroll
    for (int j = 0; j < 8; ++j) {
      int o = og*8 + j;
      float h = p0*W1[o*3] + p1*W1[o*3+1] + p2*W1[o*3+2] + b1[o];
      a1L[k][o] = fmaxf(h*sc1[o] + sh1[o], 0.f);
    }
  }
  // stage W2 into wL (XOR-swizzled rows, 16B-preserving)
  {
#pragma unroll
    for (int jj = 0; jj < 8; ++jj) {
      int f4 = t + jj*256;               // 0..2047
      int row = f4 >> 4, col4 = f4 & 15;
      float4 v = ((const float4*)W2)[f4];
      int fidx = (row*64 + col4*4) ^ (((row>>2)&7)<<2);
      *(float4*)(&wL[fidx]) = v;
    }
  }
  __syncthreads();

  // P2: h2 = a1@W2^T + b2 -> a2 = relu(bn2(h2))
  {
    int o4 = t & 31, k4 = t >> 5;
    float acc[4][4];
#pragma unroll
    for (int j = 0; j < 4; ++j) {
      float bb = b2[o4*4+j];
#pragma unroll
      for (int jk = 0; jk < 4; ++jk) acc[j][jk] = bb;
    }
    for (int ch = 0; ch < 16; ++ch) {
      float4 av[4];
#pragma unroll
      for (int jk = 0; jk < 4; ++jk)
        av[jk] = *(const float4*)(&a1L[k4*4+jk][ch*4]);
#pragma unroll
      for (int j = 0; j < 4; ++j) {
        int o = o4*4 + j;
        int fidx = (o*64 + ch*4) ^ (((o>>2)&7)<<2);
        float4 wv = *(const float4*)(&wL[fidx]);
#pragma unroll
        for (int jk = 0; jk < 4; ++jk) {
          acc[j][jk] += av[jk].x*wv.x; acc[j][jk] += av[jk].y*wv.y;
          acc[j][jk] += av[jk].z*wv.z; acc[j][jk] += av[jk].w*wv.w;
        }
      }
    }
#pragma unroll
    for (int j = 0; j < 4; ++j) {
      int o = o4*4 + j;
      float sc = sc2[o], sh = sh2[o];
#pragma unroll
      for (int jk = 0; jk < 4; ++jk)
        a2L[k4*4+jk][o] = fmaxf(acc[j][jk]*sc + sh, 0.f);
    }
  }

  // P3: 6 tiles of 64 embed channels; h3 = a2@W3^T, max over k, +b3
  int e4 = t & 15, ks = t >> 4;            // 16 e-slots x 16 k-slots
  for (int tile = 0; tile < 6; ++tile) {
    __syncthreads();
#pragma unroll
    for (int jj = 0; jj < 8; ++jj) {
      int f4 = t + jj*256;                 // 0..2047
      int row = f4 >> 5, col4 = f4 & 31;
      float4 v = ((const float4*)W3)[(size_t)(tile*64+row)*32 + col4];
      int fidx = (row*128 + col4*4) ^ (((row>>2)&7)<<2);
      *(float4*)(&wL[fidx]) = v;
    }
    __syncthreads();
    float acc[4][2];
#pragma unroll
    for (int j = 0; j < 4; ++j) { acc[j][0] = 0.f; acc[j][1] = 0.f; }
    for (int ch = 0; ch < 32; ++ch) {
      float4 av[2];
#pragma unroll
      for (int jk = 0; jk < 2; ++jk)
        av[jk] = *(const float4*)(&a2L[ks*2+jk][ch*4]);
#pragma unroll
      for (int j = 0; j < 4; ++j) {
        int e = e4*4 + j;
        int fidx = (e*128 + ch*4) ^ (((e>>2)&7)<<2);
        float4 wv = *(const float4*)(&wL[fidx]);
#pragma unroll
        for (int jk = 0; jk < 2; ++jk) {
          acc[j][jk] += av[jk].x*wv.x; acc[j][jk] += av[jk].y*wv.y;
          acc[j][jk] += av[jk].z*wv.z; acc[j][jk] += av[jk].w*wv.w;
        }
      }
    }
#pragma unroll
    for (int j = 0; j < 4; ++j)
      PM[ks][e4*4+j] = fmaxf(acc[j][0], acc[j][1]);
    __syncthreads();
    if (t < 64) {
      float mx = -3e38f;
#pragma unroll
      for (int k = 0; k < 16; ++k) mx = fmaxf(mx, PM[k][t]);
      int e = tile*64 + t;
      out[(size_t)task*C3_ + e] = mx + b3[e];
    }
  }
}

// ---------------------------------------------------------------------------
extern "C" void kernel_launch(void* const* d_in, const int* in_sizes, int n_in,
                              void* d_out, int out_size, void* d_ws, size_t ws_size,
                              hipStream_t stream) {
  (void)in_sizes; (void)n_in; (void)out_size; (void)ws_size;
  const float* x   = (const float*)d_in[0];
  const float* W1  = (const float*)d_in[1];
  const float* b1  = (const float*)d_in[2];
  const float* g1  = (const float*)d_in[3];
  const float* be1 = (const float*)d_in[4];
  const float* W2  = (const float*)d_in[5];
  const float* b2  = (const float*)d_in[6];
  const float* g2  = (const float*)d_in[7];
  const float* be2 = (const float*)d_in[8];
  const float* W3  = (const float*)d_in[9];
  const float* b3  = (const float*)d_in[10];
  float* out = (float*)d_out;
  float* ws  = (float*)d_ws;

  float* patches = ws + PATCH_OFF;
  float* centers = ws + CENT_OFF;
  float* part1   = ws + P1_OFF;
  float* sc1     = ws + SC1_OFF; float* sh1 = sc1 + C1_;
  float* part2   = ws + P2_OFF;
  float* sc2     = ws + SC2_OFF; float* sh2 = sc2 + C2_;
  float* outCent = out + (size_t)B_*S_*C3_;

  fps_kernel<<<dim3(B_), dim3(1024), 0, stream>>>(x, centers, outCent);
  qb_kernel<<<dim3(1024), dim3(256), 0, stream>>>(x, centers, patches);
  stats1_kernel<<<dim3(NB1_), dim3(256), 0, stream>>>(patches, W1, b1, part1);
  finalize_kernel<<<dim3(1), dim3(64), 0, stream>>>(part1, NB1_, C1_, g1, be1, sc1, sh1);
  stats2_kernel<<<dim3(NB2_), dim3(256), 0, stream>>>(patches, W1, b1, sc1, sh1, W2, b2, part2);
  finalize_kernel<<<dim3(1), dim3(128), 0, stream>>>(part2, NB2_, C2_, g2, be2, sc2, sh2);
  embed_kernel<<<dim3(4096), dim3(256), 0, stream>>>(patches, W1, b1, sc1, sh1,
                                                     W2, b2, sc2, sh2, W3, b3, out);
}

// Round 3
// 1111.617 us; speedup vs baseline: 2.0857x; 2.0857x over previous
//
#include <hip/hip_runtime.h>
#include <hip/hip_bf16.h>

// Problem constants
#define B_  64
#define N_  16384
#define S_  64      // NUM_PATCHES
#define K_  32      // PATCH_POINTS
#define C1_ 64
#define C2_ 128
#define C3_ 384
#define R_  (B_*S_*K_)   // 131072 rows
#define BN_EPS_ 1e-5f

// ws layout (float offsets)
#define PATCH_OFF 0
#define CENT_OFF  (R_*3)                      // 393216
#define NB1_ 512
#define P1_OFF    (CENT_OFF + B_*S_*3)        // 405504
#define SC1_OFF   (P1_OFF + NB1_*C1_*2)       // 471040
#define NB2_ 1024
#define P2_OFF    (SC1_OFF + 2*C1_)           // 471168
#define SC2_OFF   (P2_OFF + NB2_*C2_*2)       // 733312
// total ~733568 floats (~2.9 MB)

// ---------------------------------------------------------------------------
// FPS: one block (1024 threads) per batch. 16 points/thread in registers.
// Distance arithmetic replicates XLA-CPU contraction: fma(dz,dz,fma(dy,dy,dx*dx)).
// ---------------------------------------------------------------------------
__global__ __launch_bounds__(1024) void fps_kernel(const float* __restrict__ x,
        float* __restrict__ centers, float* __restrict__ outCent) {
  int b = blockIdx.x;
  int t = threadIdx.x;
  const float* xb = x + (size_t)b * N_ * 3;
  float px[16], py[16], pz[16], dist[16];
#pragma unroll
  for (int j = 0; j < 16; ++j) {
    int n = j * 1024 + t;
    px[j] = xb[n*3+0]; py[j] = xb[n*3+1]; pz[j] = xb[n*3+2];
    dist[j] = 1e10f;
  }
  __shared__ float cb[3];
  __shared__ float wd[16]; __shared__ int wi[16];
  __shared__ float wx[16], wy[16], wz[16];
  if (t == 0) { cb[0] = px[0]; cb[1] = py[0]; cb[2] = pz[0]; }
  int lane = t & 63, wv = t >> 6;
  for (int s = 0; s < S_; ++s) {
    __syncthreads();
    float cx = cb[0], cy = cb[1], cz = cb[2];
    if (t == 0) {
      int task = b * S_ + s;
      centers[task*3+0] = cx; centers[task*3+1] = cy; centers[task*3+2] = cz;
      outCent[task*3+0] = cx; outCent[task*3+1] = cy; outCent[task*3+2] = cz;
    }
    float bd = -1.0f; int bn = 0; float bx = 0.f, by = 0.f, bz = 0.f;
#pragma unroll
    for (int j = 0; j < 16; ++j) {
      float dx = px[j]-cx, dy = py[j]-cy, dz = pz[j]-cz;
      float d = __builtin_fmaf(dz, dz, __builtin_fmaf(dy, dy, dx*dx));
      float dm = fminf(dist[j], d);
      dist[j] = dm;
      int n = j*1024 + t;
      if (dm > bd) { bd = dm; bn = n; bx = px[j]; by = py[j]; bz = pz[j]; }
    }
#pragma unroll
    for (int m = 1; m < 64; m <<= 1) {
      float od = __shfl_xor(bd, m, 64); int on = __shfl_xor(bn, m, 64);
      float ox = __shfl_xor(bx, m, 64), oy = __shfl_xor(by, m, 64), oz = __shfl_xor(bz, m, 64);
      if (od > bd || (od == bd && on < bn)) { bd = od; bn = on; bx = ox; by = oy; bz = oz; }
    }
    if (lane == 0) { wd[wv] = bd; wi[wv] = bn; wx[wv] = bx; wy[wv] = by; wz[wv] = bz; }
    __syncthreads();
    if (t < 16) {
      bd = wd[t]; bn = wi[t]; bx = wx[t]; by = wy[t]; bz = wz[t];
#pragma unroll
      for (int m = 1; m < 16; m <<= 1) {
        float od = __shfl_xor(bd, m, 64); int on = __shfl_xor(bn, m, 64);
        float ox = __shfl_xor(bx, m, 64), oy = __shfl_xor(by, m, 64), oz = __shfl_xor(bz, m, 64);
        if (od > bd || (od == bd && on < bn)) { bd = od; bn = on; bx = ox; by = oy; bz = oz; }
      }
      if (t == 0) { cb[0] = bx; cb[1] = by; cb[2] = bz; }
    }
  }
}

// ---------------------------------------------------------------------------
// query_ball REWRITE: one block (256 threads) per (b,s) task. 64 keys/thread
// in registers; exact 32nd-smallest via 32-pass radix bisection on the
// monotone uint map of the distance; collect set {key<T} + index-ordered
// ties; canonical index sort of the 32 winners (deterministic output).
// Distance replicates XLA contraction exactly (same as passing R2 version).
// ---------------------------------------------------------------------------
__global__ __launch_bounds__(256) void qb_kernel(const float* __restrict__ x,
        const float* __restrict__ centers, float* __restrict__ patches) {
  int t = threadIdx.x;
  int task = blockIdx.x;
  int b = task >> 6;
  const float* xb = x + (size_t)b * N_ * 3;
  float cx = centers[task*3+0], cy = centers[task*3+1], cz = centers[task*3+2];
  float A = __builtin_fmaf(cz, cz, __builtin_fmaf(cy, cy, cx*cx));

  __shared__ unsigned int wcnt[33][4];
  __shared__ unsigned int redMin[4];
  __shared__ int idxL[40];
  __shared__ int sortedIdx[32];
  __shared__ unsigned int cntA;
  if (t == 0) cntA = 0u;

  unsigned int key[64];
#pragma unroll
  for (int j = 0; j < 64; ++j) {
    int n = j * 256 + t;
    float qx = xb[n*3+0], qy = xb[n*3+1], qz = xb[n*3+2];
    float Bn = __builtin_fmaf(qz, qz, __builtin_fmaf(qy, qy, qx*qx));
    float dt = __builtin_fmaf(cz, qz, __builtin_fmaf(cy, qy, cx*qx));
    float d  = __builtin_fmaf(-2.0f, dt, A + Bn);
    unsigned int u = __float_as_uint(d);
    key[j] = (u & 0x80000000u) ? ~u : (u | 0x80000000u);
  }
  int lane = t & 63, wv = t >> 6;

  // radix bisection for T = 32nd smallest key
  unsigned int result = 0u;
  for (int bit = 31; bit >= 0; --bit) {
    unsigned int tryv = result | (1u << bit);
    int c = 0;
#pragma unroll
    for (int j = 0; j < 64; ++j) c += (key[j] < tryv) ? 1 : 0;
#pragma unroll
    for (int m = 1; m < 64; m <<= 1) c += __shfl_xor(c, m, 64);
    if (lane == 0) wcnt[31 - bit][wv] = (unsigned int)c;
    __syncthreads();
    unsigned int tot = wcnt[31-bit][0] + wcnt[31-bit][1] + wcnt[31-bit][2] + wcnt[31-bit][3];
    if (tot < 32u) result = tryv;
  }
  unsigned int T = result;

  // exact count of strictly-less
  {
    int c = 0;
#pragma unroll
    for (int j = 0; j < 64; ++j) c += (key[j] < T) ? 1 : 0;
#pragma unroll
    for (int m = 1; m < 64; m <<= 1) c += __shfl_xor(c, m, 64);
    if (lane == 0) wcnt[32][wv] = (unsigned int)c;
  }
  __syncthreads();
  unsigned int totLess = wcnt[32][0] + wcnt[32][1] + wcnt[32][2] + wcnt[32][3];

  // collect strict-less set (order within set arbitrary; canonicalized below)
#pragma unroll
  for (int j = 0; j < 64; ++j) {
    if (key[j] < T) {
      unsigned int p = atomicAdd(&cntA, 1u);
      idxL[p] = j * 256 + t;
    }
  }

  // ties at T: take (32 - totLess) smallest indices, deterministic extraction
  int m_need = 32 - (int)totLess;   // >= 1 by construction
  int picked = -1;
  for (int r = 0; r < m_need; ++r) {
    int cand = 0x7fffffff;
#pragma unroll
    for (int j = 0; j < 64; ++j) {
      int n = j * 256 + t;
      if (key[j] == T && n > picked && n < cand) cand = n;
    }
#pragma unroll
    for (int m = 1; m < 64; m <<= 1) cand = min(cand, __shfl_xor(cand, m, 64));
    if (lane == 0) redMin[wv] = (unsigned int)cand;
    __syncthreads();
    int winner = (int)min(min(redMin[0], redMin[1]), min(redMin[2], redMin[3]));
    if (t == 0) idxL[(int)totLess + r] = winner;
    picked = winner;
    __syncthreads();
  }

  // canonical sort of the 32 indices -> bitwise-deterministic patch order
  if (t < 32) {
    int v = idxL[t];
    int rank = 0;
#pragma unroll
    for (int j = 0; j < 32; ++j) rank += (idxL[j] < v) ? 1 : 0;
    sortedIdx[rank] = v;
  }
  __syncthreads();
  if (t < 32) {
    int n = sortedIdx[t];
    float qx = xb[n*3+0], qy = xb[n*3+1], qz = xb[n*3+2];
    size_t row = (size_t)task * K_ + t;
    patches[row*3+0] = qx - cx;
    patches[row*3+1] = qy - cy;
    patches[row*3+2] = qz - cz;
  }
}

// ---------------------------------------------------------------------------
// stats1: per-channel sum / sumsq of h1 = patches@W1^T + b1 (no h1 store)
// ---------------------------------------------------------------------------
__global__ __launch_bounds__(256) void stats1_kernel(const float* __restrict__ patches,
        const float* __restrict__ W1, const float* __restrict__ b1,
        float* __restrict__ part) {
  int t = threadIdx.x;
  int o = t & 63, rg = t >> 6;
  float w0 = W1[o*3+0], w1 = W1[o*3+1], w2 = W1[o*3+2], bb = b1[o];
  int r0 = blockIdx.x * 256 + rg * 64;
  float s1 = 0.f, s2 = 0.f;
  for (int i = 0; i < 64; ++i) {
    const float* p = patches + (size_t)(r0 + i) * 3;
    float h = p[0]*w0 + p[1]*w1 + p[2]*w2 + bb;
    s1 += h; s2 += h*h;
  }
  __shared__ float red[4][64][2];
  red[rg][o][0] = s1; red[rg][o][1] = s2;
  __syncthreads();
  if (t < 64) {
    float a = red[0][t][0] + red[1][t][0] + red[2][t][0] + red[3][t][0];
    float c = red[0][t][1] + red[1][t][1] + red[2][t][1] + red[3][t][1];
    part[blockIdx.x*128 + t*2 + 0] = a;
    part[blockIdx.x*128 + t*2 + 1] = c;
  }
}

// ---------------------------------------------------------------------------
// finalize: deterministic sum of partials -> scale/shift (BN affine form)
// ---------------------------------------------------------------------------
__global__ void finalize_kernel(const float* __restrict__ part, int nblk, int nch,
        const float* __restrict__ g, const float* __restrict__ be,
        float* __restrict__ scale, float* __restrict__ shift) {
  int o = threadIdx.x;
  if (o >= nch) return;
  double s1 = 0.0, s2 = 0.0;
  for (int i = 0; i < nblk; ++i) {
    s1 += (double)part[i*nch*2 + o*2 + 0];
    s2 += (double)part[i*nch*2 + o*2 + 1];
  }
  float m   = (float)(s1 / (double)R_);
  float eh2 = (float)(s2 / (double)R_);
  float v = eh2 - m*m;
  float rs = rsqrtf(v + BN_EPS_);
  float sc = g[o] * rs;
  scale[o] = sc;
  shift[o] = be[o] - m*sc;
}

// ---------------------------------------------------------------------------
// stats2: recompute a1 tile (LDS), h2 = a1@W2^T + b2, per-channel sum/sumsq
// ---------------------------------------------------------------------------
__global__ __launch_bounds__(256) void stats2_kernel(const float* __restrict__ patches,
        const float* __restrict__ W1, const float* __restrict__ b1,
        const float* __restrict__ sc1, const float* __restrict__ sh1,
        const float* __restrict__ W2, const float* __restrict__ b2,
        float* __restrict__ part) {
  __shared__ float a1L[128][68];
  __shared__ float red[2][128][2];
  int t = threadIdx.x;
  int r0 = blockIdx.x * 128;
  {
    int r = t & 127, oh = t >> 7;
    const float* p = patches + (size_t)(r0 + r) * 3;
    float p0 = p[0], p1 = p[1], p2 = p[2];
#pragma unroll
    for (int j = 0; j < 32; ++j) {
      int o = oh*32 + j;
      float h = p0*W1[o*3] + p1*W1[o*3+1] + p2*W1[o*3+2] + b1[o];
      a1L[r][o] = fmaxf(h*sc1[o] + sh1[o], 0.f);
    }
  }
  __syncthreads();
  int o = t & 127, rg = t >> 7;
  float4 wreg[16];
  const float4* w2r = (const float4*)(W2 + o*64);
#pragma unroll
  for (int c = 0; c < 16; ++c) wreg[c] = w2r[c];
  float bb = b2[o];
  float s1 = 0.f, s2 = 0.f;
  for (int i = 0; i < 64; ++i) {
    int r = rg*64 + i;
    float acc = bb;
    const float4* a4 = (const float4*)(&a1L[r][0]);
#pragma unroll
    for (int c = 0; c < 16; ++c) {
      float4 a = a4[c];
      acc += a.x*wreg[c].x; acc += a.y*wreg[c].y;
      acc += a.z*wreg[c].z; acc += a.w*wreg[c].w;
    }
    s1 += acc; s2 += acc*acc;
  }
  red[rg][o][0] = s1; red[rg][o][1] = s2;
  __syncthreads();
  if (t < 128) {
    part[blockIdx.x*256 + t*2 + 0] = red[0][t][0] + red[1][t][0];
    part[blockIdx.x*256 + t*2 + 1] = red[0][t][1] + red[1][t][1];
  }
}

// ---------------------------------------------------------------------------
// embed: per (b,s): patches -> a1 -> a2 (LDS) -> layer3 (LDS-staged swizzled
// W3 tiles, 4e x 2k register tiles) -> max over K -> out. b3 added after max.
// ---------------------------------------------------------------------------
__global__ __launch_bounds__(256) void embed_kernel(const float* __restrict__ patches,
        const float* __restrict__ W1, const float* __restrict__ b1,
        const float* __restrict__ sc1, const float* __restrict__ sh1,
        const float* __restrict__ W2, const float* __restrict__ b2,
        const float* __restrict__ sc2, const float* __restrict__ sh2,
        const float* __restrict__ W3, const float* __restrict__ b3,
        float* __restrict__ out) {
  __shared__ float a1L[32][68];     // 8704 B
  __shared__ float a2L[32][132];    // 16896 B
  __shared__ float wL[8192];        // 32 KB: W2 (swz) for P2, W3 tile (swz) for P3
  __shared__ float PM[16][64];      // 4 KB partial-max
  int t = threadIdx.x;
  int task = blockIdx.x;

  // P1: a1 = relu(bn1(patches@W1^T + b1))
  {
    int k = t & 31, og = t >> 5;
    const float* p = patches + ((size_t)task*K_ + k)*3;
    float p0 = p[0], p1 = p[1], p2 = p[2];
#pragma unroll
    for (int j = 0; j < 8; ++j) {
      int o = og*8 + j;
      float h = p0*W1[o*3] + p1*W1[o*3+1] + p2*W1[o*3+2] + b1[o];
      a1L[k][o] = fmaxf(h*sc1[o] + sh1[o], 0.f);
    }
  }
  // stage W2 into wL (XOR-swizzled rows, 16B-preserving)
  {
#pragma unroll
    for (int jj = 0; jj < 8; ++jj) {
      int f4 = t + jj*256;               // 0..2047
      int row = f4 >> 4, col4 = f4 & 15;
      float4 v = ((const float4*)W2)[f4];
      int fidx = (row*64 + col4*4) ^ (((row>>2)&7)<<2);
      *(float4*)(&wL[fidx]) = v;
    }
  }
  __syncthreads();

  // P2: h2 = a1@W2^T + b2 -> a2 = relu(bn2(h2))
  {
    int o4 = t & 31, k4 = t >> 5;
    float acc[4][4];
#pragma unroll
    for (int j = 0; j < 4; ++j) {
      float bb = b2[o4*4+j];
#pragma unroll
      for (int jk = 0; jk < 4; ++jk) acc[j][jk] = bb;
    }
    for (int ch = 0; ch < 16; ++ch) {
      float4 av[4];
#pragma unroll
      for (int jk = 0; jk < 4; ++jk)
        av[jk] = *(const float4*)(&a1L[k4*4+jk][ch*4]);
#pragma unroll
      for (int j = 0; j < 4; ++j) {
        int o = o4*4 + j;
        int fidx = (o*64 + ch*4) ^ (((o>>2)&7)<<2);
        float4 wv = *(const float4*)(&wL[fidx]);
#pragma unroll
        for (int jk = 0; jk < 4; ++jk) {
          acc[j][jk] += av[jk].x*wv.x; acc[j][jk] += av[jk].y*wv.y;
          acc[j][jk] += av[jk].z*wv.z; acc[j][jk] += av[jk].w*wv.w;
        }
      }
    }
#pragma unroll
    for (int j = 0; j < 4; ++j) {
      int o = o4*4 + j;
      float sc = sc2[o], sh = sh2[o];
#pragma unroll
      for (int jk = 0; jk < 4; ++jk)
        a2L[k4*4+jk][o] = fmaxf(acc[j][jk]*sc + sh, 0.f);
    }
  }

  // P3: 6 tiles of 64 embed channels; h3 = a2@W3^T, max over k, +b3
  int e4 = t & 15, ks = t >> 4;            // 16 e-slots x 16 k-slots
  for (int tile = 0; tile < 6; ++tile) {
    __syncthreads();
#pragma unroll
    for (int jj = 0; jj < 8; ++jj) {
      int f4 = t + jj*256;                 // 0..2047
      int row = f4 >> 5, col4 = f4 & 31;
      float4 v = ((const float4*)W3)[(size_t)(tile*64+row)*32 + col4];
      int fidx = (row*128 + col4*4) ^ (((row>>2)&7)<<2);
      *(float4*)(&wL[fidx]) = v;
    }
    __syncthreads();
    float acc[4][2];
#pragma unroll
    for (int j = 0; j < 4; ++j) { acc[j][0] = 0.f; acc[j][1] = 0.f; }
    for (int ch = 0; ch < 32; ++ch) {
      float4 av[2];
#pragma unroll
      for (int jk = 0; jk < 2; ++jk)
        av[jk] = *(const float4*)(&a2L[ks*2+jk][ch*4]);
#pragma unroll
      for (int j = 0; j < 4; ++j) {
        int e = e4*4 + j;
        int fidx = (e*128 + ch*4) ^ (((e>>2)&7)<<2);
        float4 wv = *(const float4*)(&wL[fidx]);
#pragma unroll
        for (int jk = 0; jk < 2; ++jk) {
          acc[j][jk] += av[jk].x*wv.x; acc[j][jk] += av[jk].y*wv.y;
          acc[j][jk] += av[jk].z*wv.z; acc[j][jk] += av[jk].w*wv.w;
        }
      }
    }
#pragma unroll
    for (int j = 0; j < 4; ++j)
      PM[ks][e4*4+j] = fmaxf(acc[j][0], acc[j][1]);
    __syncthreads();
    if (t < 64) {
      float mx = -3e38f;
#pragma unroll
      for (int k = 0; k < 16; ++k) mx = fmaxf(mx, PM[k][t]);
      int e = tile*64 + t;
      out[(size_t)task*C3_ + e] = mx + b3[e];
    }
  }
}

// ---------------------------------------------------------------------------
extern "C" void kernel_launch(void* const* d_in, const int* in_sizes, int n_in,
                              void* d_out, int out_size, void* d_ws, size_t ws_size,
                              hipStream_t stream) {
  (void)in_sizes; (void)n_in; (void)out_size; (void)ws_size;
  const float* x   = (const float*)d_in[0];
  const float* W1  = (const float*)d_in[1];
  const float* b1  = (const float*)d_in[2];
  const float* g1  = (const float*)d_in[3];
  const float* be1 = (const float*)d_in[4];
  const float* W2  = (const float*)d_in[5];
  const float* b2  = (const float*)d_in[6];
  const float* g2  = (const float*)d_in[7];
  const float* be2 = (const float*)d_in[8];
  const float* W3  = (const float*)d_in[9];
  const float* b3  = (const float*)d_in[10];
  float* out = (float*)d_out;
  float* ws  = (float*)d_ws;

  float* patches = ws + PATCH_OFF;
  float* centers = ws + CENT_OFF;
  float* part1   = ws + P1_OFF;
  float* sc1     = ws + SC1_OFF; float* sh1 = sc1 + C1_;
  float* part2   = ws + P2_OFF;
  float* sc2     = ws + SC2_OFF; float* sh2 = sc2 + C2_;
  float* outCent = out + (size_t)B_*S_*C3_;

  fps_kernel<<<dim3(B_), dim3(1024), 0, stream>>>(x, centers, outCent);
  qb_kernel<<<dim3(4096), dim3(256), 0, stream>>>(x, centers, patches);
  stats1_kernel<<<dim3(NB1_), dim3(256), 0, stream>>>(patches, W1, b1, part1);
  finalize_kernel<<<dim3(1), dim3(64), 0, stream>>>(part1, NB1_, C1_, g1, be1, sc1, sh1);
  stats2_kernel<<<dim3(NB2_), dim3(256), 0, stream>>>(patches, W1, b1, sc1, sh1, W2, b2, part2);
  finalize_kernel<<<dim3(1), dim3(128), 0, stream>>>(part2, NB2_, C2_, g2, be2, sc2, sh2);
  embed_kernel<<<dim3(4096), dim3(256), 0, stream>>>(patches, W1, b1, sc1, sh1,
                                                     W2, b2, sc2, sh2, W3, b3, out);
}

// Round 4
// 727.920 us; speedup vs baseline: 3.1851x; 1.5271x over previous
//
#include <hip/hip_runtime.h>
#include <hip/hip_bf16.h>

// Problem constants
#define B_  64
#define N_  16384
#define S_  64      // NUM_PATCHES
#define K_  32      // PATCH_POINTS
#define C1_ 64
#define C2_ 128
#define C3_ 384
#define R_  (B_*S_*K_)   // 131072 rows
#define BN_EPS_ 1e-5f

// ws layout (float offsets)
#define PATCH_OFF 0
#define CENT_OFF  (R_*3)                      // 393216
#define NB1_ 256
#define P1_OFF    (CENT_OFF + B_*S_*3)        // 405504
#define SC1_OFF   (P1_OFF + NB1_*C1_*2)       // 438272
#define NB2_ 256
#define P2_OFF    (SC1_OFF + 2*C1_)           // 438400
#define SC2_OFF   (P2_OFF + NB2_*C2_*2)       // 503936
#define W2BF_OFF  (SC2_OFF + 2*C2_)           // 504192 (floats; holds 8192 shorts)
#define W3BF_OFF  (W2BF_OFF + 4096)           // 508288 (floats; holds 49152 shorts)
// end = 532864 floats (~2.13 MB) — below previously-proven ws usage

typedef short bf16x8 __attribute__((ext_vector_type(8)));
typedef float f32x4  __attribute__((ext_vector_type(4)));

static __device__ __forceinline__ unsigned short f2bf(float f) {
  unsigned u = __float_as_uint(f);
  unsigned r = (u + 0x7fffu + ((u >> 16) & 1u)) >> 16;   // RNE
  return (unsigned short)r;
}

// ---------------------------------------------------------------------------
// prep: convert W2 (128x64) and W3 (384x128) to bf16, row-major (plain).
// ---------------------------------------------------------------------------
__global__ void prep_kernel(const float* __restrict__ W2, const float* __restrict__ W3,
                            short* __restrict__ w2bf, short* __restrict__ w3bf) {
  int i = blockIdx.x * 256 + threadIdx.x;
  if (i < C2_*C1_) w2bf[i] = (short)f2bf(W2[i]);
  int j = i - C2_*C1_;
  if (j >= 0 && j < C3_*C2_) w3bf[j] = (short)f2bf(W3[j]);
}

// ---------------------------------------------------------------------------
// FPS: one block (1024 threads) per batch. 16 points/thread in registers.
// Distance arithmetic replicates XLA-CPU contraction: fma(dz,dz,fma(dy,dy,dx*dx)).
// ---------------------------------------------------------------------------
__global__ __launch_bounds__(1024) void fps_kernel(const float* __restrict__ x,
        float* __restrict__ centers, float* __restrict__ outCent) {
  int b = blockIdx.x;
  int t = threadIdx.x;
  const float* xb = x + (size_t)b * N_ * 3;
  float px[16], py[16], pz[16], dist[16];
#pragma unroll
  for (int j = 0; j < 16; ++j) {
    int n = j * 1024 + t;
    px[j] = xb[n*3+0]; py[j] = xb[n*3+1]; pz[j] = xb[n*3+2];
    dist[j] = 1e10f;
  }
  __shared__ float cb[3];
  __shared__ float wd[16]; __shared__ int wi[16];
  __shared__ float wx[16], wy[16], wz[16];
  if (t == 0) { cb[0] = px[0]; cb[1] = py[0]; cb[2] = pz[0]; }
  int lane = t & 63, wv = t >> 6;
  for (int s = 0; s < S_; ++s) {
    __syncthreads();
    float cx = cb[0], cy = cb[1], cz = cb[2];
    if (t == 0) {
      int task = b * S_ + s;
      centers[task*3+0] = cx; centers[task*3+1] = cy; centers[task*3+2] = cz;
      outCent[task*3+0] = cx; outCent[task*3+1] = cy; outCent[task*3+2] = cz;
    }
    float bd = -1.0f; int bn = 0; float bx = 0.f, by = 0.f, bz = 0.f;
#pragma unroll
    for (int j = 0; j < 16; ++j) {
      float dx = px[j]-cx, dy = py[j]-cy, dz = pz[j]-cz;
      float d = __builtin_fmaf(dz, dz, __builtin_fmaf(dy, dy, dx*dx));
      float dm = fminf(dist[j], d);
      dist[j] = dm;
      int n = j*1024 + t;
      if (dm > bd) { bd = dm; bn = n; bx = px[j]; by = py[j]; bz = pz[j]; }
    }
#pragma unroll
    for (int m = 1; m < 64; m <<= 1) {
      float od = __shfl_xor(bd, m, 64); int on = __shfl_xor(bn, m, 64);
      float ox = __shfl_xor(bx, m, 64), oy = __shfl_xor(by, m, 64), oz = __shfl_xor(bz, m, 64);
      if (od > bd || (od == bd && on < bn)) { bd = od; bn = on; bx = ox; by = oy; bz = oz; }
    }
    if (lane == 0) { wd[wv] = bd; wi[wv] = bn; wx[wv] = bx; wy[wv] = by; wz[wv] = bz; }
    __syncthreads();
    if (t < 16) {
      bd = wd[t]; bn = wi[t]; bx = wx[t]; by = wy[t]; bz = wz[t];
#pragma unroll
      for (int m = 1; m < 16; m <<= 1) {
        float od = __shfl_xor(bd, m, 64); int on = __shfl_xor(bn, m, 64);
        float ox = __shfl_xor(bx, m, 64), oy = __shfl_xor(by, m, 64), oz = __shfl_xor(bz, m, 64);
        if (od > bd || (od == bd && on < bn)) { bd = od; bn = on; bx = ox; by = oy; bz = oz; }
      }
      if (t == 0) { cb[0] = bx; cb[1] = by; cb[2] = bz; }
    }
  }
}

// ---------------------------------------------------------------------------
// query_ball: one block (256 threads) per (b,s). Exact 32-NN via radix
// bisection on the monotone uint map of the XLA-contracted distance.
// ---------------------------------------------------------------------------
__global__ __launch_bounds__(256) void qb_kernel(const float* __restrict__ x,
        const float* __restrict__ centers, float* __restrict__ patches) {
  int t = threadIdx.x;
  int task = blockIdx.x;
  int b = task >> 6;
  const float* xb = x + (size_t)b * N_ * 3;
  float cx = centers[task*3+0], cy = centers[task*3+1], cz = centers[task*3+2];
  float A = __builtin_fmaf(cz, cz, __builtin_fmaf(cy, cy, cx*cx));

  __shared__ unsigned int wcnt[33][4];
  __shared__ unsigned int redMin[4];
  __shared__ int idxL[40];
  __shared__ int sortedIdx[32];
  __shared__ unsigned int cntA;
  if (t == 0) cntA = 0u;

  unsigned int key[64];
#pragma unroll
  for (int j = 0; j < 64; ++j) {
    int n = j * 256 + t;
    float qx = xb[n*3+0], qy = xb[n*3+1], qz = xb[n*3+2];
    float Bn = __builtin_fmaf(qz, qz, __builtin_fmaf(qy, qy, qx*qx));
    float dt = __builtin_fmaf(cz, qz, __builtin_fmaf(cy, qy, cx*qx));
    float d  = __builtin_fmaf(-2.0f, dt, A + Bn);
    unsigned int u = __float_as_uint(d);
    key[j] = (u & 0x80000000u) ? ~u : (u | 0x80000000u);
  }
  int lane = t & 63, wv = t >> 6;

  unsigned int result = 0u;
  for (int bit = 31; bit >= 0; --bit) {
    unsigned int tryv = result | (1u << bit);
    int c = 0;
#pragma unroll
    for (int j = 0; j < 64; ++j) c += (key[j] < tryv) ? 1 : 0;
#pragma unroll
    for (int m = 1; m < 64; m <<= 1) c += __shfl_xor(c, m, 64);
    if (lane == 0) wcnt[31 - bit][wv] = (unsigned int)c;
    __syncthreads();
    unsigned int tot = wcnt[31-bit][0] + wcnt[31-bit][1] + wcnt[31-bit][2] + wcnt[31-bit][3];
    if (tot < 32u) result = tryv;
  }
  unsigned int T = result;

  {
    int c = 0;
#pragma unroll
    for (int j = 0; j < 64; ++j) c += (key[j] < T) ? 1 : 0;
#pragma unroll
    for (int m = 1; m < 64; m <<= 1) c += __shfl_xor(c, m, 64);
    if (lane == 0) wcnt[32][wv] = (unsigned int)c;
  }
  __syncthreads();
  unsigned int totLess = wcnt[32][0] + wcnt[32][1] + wcnt[32][2] + wcnt[32][3];

#pragma unroll
  for (int j = 0; j < 64; ++j) {
    if (key[j] < T) {
      unsigned int p = atomicAdd(&cntA, 1u);
      idxL[p] = j * 256 + t;
    }
  }

  int m_need = 32 - (int)totLess;
  int picked = -1;
  for (int r = 0; r < m_need; ++r) {
    int cand = 0x7fffffff;
#pragma unroll
    for (int j = 0; j < 64; ++j) {
      int n = j * 256 + t;
      if (key[j] == T && n > picked && n < cand) cand = n;
    }
#pragma unroll
    for (int m = 1; m < 64; m <<= 1) cand = min(cand, __shfl_xor(cand, m, 64));
    if (lane == 0) redMin[wv] = (unsigned int)cand;
    __syncthreads();
    int winner = (int)min(min(redMin[0], redMin[1]), min(redMin[2], redMin[3]));
    if (t == 0) idxL[(int)totLess + r] = winner;
    picked = winner;
    __syncthreads();
  }

  if (t < 32) {
    int v = idxL[t];
    int rank = 0;
#pragma unroll
    for (int j = 0; j < 32; ++j) rank += (idxL[j] < v) ? 1 : 0;
    sortedIdx[rank] = v;
  }
  __syncthreads();
  if (t < 32) {
    int n = sortedIdx[t];
    float qx = xb[n*3+0], qy = xb[n*3+1], qz = xb[n*3+2];
    size_t row = (size_t)task * K_ + t;
    patches[row*3+0] = qx - cx;
    patches[row*3+1] = qy - cy;
    patches[row*3+2] = qz - cz;
  }
}

// ---------------------------------------------------------------------------
// stats1: per-channel sum / sumsq of h1 (256 blocks x 512 rows)
// ---------------------------------------------------------------------------
__global__ __launch_bounds__(256) void stats1_kernel(const float* __restrict__ patches,
        const float* __restrict__ W1, const float* __restrict__ b1,
        float* __restrict__ part) {
  int t = threadIdx.x;
  int o = t & 63, rg = t >> 6;
  float w0 = W1[o*3+0], w1 = W1[o*3+1], w2 = W1[o*3+2], bb = b1[o];
  int r0 = blockIdx.x * 512 + rg * 128;
  float s1 = 0.f, s2 = 0.f;
  for (int i = 0; i < 128; ++i) {
    const float* p = patches + (size_t)(r0 + i) * 3;
    float h = p[0]*w0 + p[1]*w1 + p[2]*w2 + bb;
    s1 += h; s2 += h*h;
  }
  __shared__ float red[4][64][2];
  red[rg][o][0] = s1; red[rg][o][1] = s2;
  __syncthreads();
  if (t < 64) {
    float a = red[0][t][0] + red[1][t][0] + red[2][t][0] + red[3][t][0];
    float c = red[0][t][1] + red[1][t][1] + red[2][t][1] + red[3][t][1];
    part[blockIdx.x*128 + t*2 + 0] = a;
    part[blockIdx.x*128 + t*2 + 1] = c;
  }
}

// ---------------------------------------------------------------------------
// finalize: deterministic sum of partials -> scale/shift (BN affine form).
// If bias != nullptr, folds a pre-BN linear bias into shift (for MFMA path
// that computes h without bias): shift = be - m*sc + bias*sc.
// ---------------------------------------------------------------------------
__global__ void finalize_kernel(const float* __restrict__ part, int nblk, int nch,
        const float* __restrict__ g, const float* __restrict__ be,
        const float* __restrict__ bias,
        float* __restrict__ scale, float* __restrict__ shift) {
  int o = threadIdx.x;
  if (o >= nch) return;
  double s1 = 0.0, s2 = 0.0;
  for (int i = 0; i < nblk; ++i) {
    s1 += (double)part[i*nch*2 + o*2 + 0];
    s2 += (double)part[i*nch*2 + o*2 + 1];
  }
  float m   = (float)(s1 / (double)R_);
  float eh2 = (float)(s2 / (double)R_);
  float v = eh2 - m*m;
  float rs = rsqrtf(v + BN_EPS_);
  float sc = g[o] * rs;
  scale[o] = sc;
  float sh = be[o] - m*sc;
  if (bias) sh += bias[o]*sc;
  shift[o] = sh;
}

// ---------------------------------------------------------------------------
// stats2: 256 blocks x 512 rows (4 tiles of 128): recompute a1 tile (LDS),
// h2 = a1@W2^T + b2 (fp32), per-channel sum/sumsq.
// ---------------------------------------------------------------------------
__global__ __launch_bounds__(256) void stats2_kernel(const float* __restrict__ patches,
        const float* __restrict__ W1, const float* __restrict__ b1,
        const float* __restrict__ sc1, const float* __restrict__ sh1,
        const float* __restrict__ W2, const float* __restrict__ b2,
        float* __restrict__ part) {
  __shared__ float a1L[128][68];
  __shared__ float red[2][128][2];
  int t = threadIdx.x;
  float4 wreg[16];
  const float4* w2r = (const float4*)(W2 + (t & 127)*64);
#pragma unroll
  for (int c = 0; c < 16; ++c) wreg[c] = w2r[c];
  float bb = b2[t & 127];
  float s1 = 0.f, s2 = 0.f;
  int rg = t >> 7;
  for (int tile = 0; tile < 4; ++tile) {
    int r0 = blockIdx.x * 512 + tile * 128;
    {
      int r = t & 127, oh = t >> 7;
      const float* p = patches + (size_t)(r0 + r) * 3;
      float p0 = p[0], p1 = p[1], p2 = p[2];
#pragma unroll
      for (int j = 0; j < 32; ++j) {
        int o = oh*32 + j;
        float h = p0*W1[o*3] + p1*W1[o*3+1] + p2*W1[o*3+2] + b1[o];
        a1L[r][o] = fmaxf(h*sc1[o] + sh1[o], 0.f);
      }
    }
    __syncthreads();
    for (int i = 0; i < 64; ++i) {
      int r = rg*64 + i;
      float acc = bb;
      const float4* a4 = (const float4*)(&a1L[r][0]);
#pragma unroll
      for (int c = 0; c < 16; ++c) {
        float4 a = a4[c];
        acc += a.x*wreg[c].x; acc += a.y*wreg[c].y;
        acc += a.z*wreg[c].z; acc += a.w*wreg[c].w;
      }
      s1 += acc; s2 += acc*acc;
    }
    __syncthreads();
  }
  red[rg][t & 127][0] = s1; red[rg][t & 127][1] = s2;
  __syncthreads();
  if (t < 128) {
    part[blockIdx.x*256 + t*2 + 0] = red[0][t][0] + red[1][t][0];
    part[blockIdx.x*256 + t*2 + 1] = red[0][t][1] + red[1][t][1];
  }
}

// ---------------------------------------------------------------------------
// embed (MFMA): 4 tasks/block (M=128 rows), 256 threads (4 waves, 1 task/wave).
// P1: a1 fp32 -> bf16 LDS [128][64ch], 128B rows, slot-XOR swizzle.
// P2: h2 = a1 @ W2^T via mfma_16x16x32_bf16 (K=64), W2 B-frags from global
//     (L1-resident). BN2(+b2 folded)+ReLU -> a2 bf16 LDS [128][128ch] swz.
// P3: h3 = a2 @ W3^T (K=128, N=384), W3 B-frags from global; A-frags hoisted.
//     max over 32 rows via vmax + 2 shfl; +b3; write.
// Frag maps (m89-verified C/D): A/B lane l: 16-idx = l&15, k = (l>>4)*8+j;
// D: col = l&15, row = (l>>4)*4 + reg.
// ---------------------------------------------------------------------------
__global__ __launch_bounds__(256) void embed_kernel(
        const float* __restrict__ patches,
        const float* __restrict__ W1, const float* __restrict__ b1,
        const float* __restrict__ sc1, const float* __restrict__ sh1,
        const short* __restrict__ w2bf, const float* __restrict__ sc2,
        const float* __restrict__ sh2f,
        const short* __restrict__ w3bf, const float* __restrict__ b3,
        float* __restrict__ out) {
  __shared__ char lds[49152];   // a1L @0 (16KB), a2L @16384 (32KB)
  int t = threadIdx.x;
  int l = t & 63, w = t >> 6;
  int lo = l & 15, hi = l >> 4;

  // ---- P1 ----
  {
    int row = t >> 1, half = t & 1;
    const float* p = patches + ((size_t)blockIdx.x*128 + row)*3;
    float p0 = p[0], p1 = p[1], p2 = p[2];
    int swz = (row & 7) << 4;
    char* dst = lds + row*128;
#pragma unroll
    for (int g = 0; g < 4; ++g) {
      unsigned short pk[8];
#pragma unroll
      for (int j = 0; j < 8; ++j) {
        int o = half*32 + g*8 + j;
        float h = p0*W1[o*3] + p1*W1[o*3+1] + p2*W1[o*3+2] + b1[o];
        pk[j] = f2bf(fmaxf(h*sc1[o] + sh1[o], 0.f));
      }
      int4 v;
      v.x = pk[0] | (pk[1]<<16); v.y = pk[2] | (pk[3]<<16);
      v.z = pk[4] | (pk[5]<<16); v.w = pk[6] | (pk[7]<<16);
      *(int4*)(dst + (((half*64 + g*16)) ^ swz)) = v;
    }
  }
  __syncthreads();

  // ---- P2 ----
  {
    bf16x8 af[2][2];
#pragma unroll
    for (int mt = 0; mt < 2; ++mt) {
      int row = w*32 + mt*16 + lo;
#pragma unroll
      for (int ks = 0; ks < 2; ++ks)
        af[mt][ks] = *(const bf16x8*)(lds + row*128 + ((ks*64 + hi*16) ^ ((row&7)<<4)));
    }
#pragma unroll
    for (int nt = 0; nt < 8; ++nt) {
      f32x4 acc0 = {0.f,0.f,0.f,0.f}, acc1 = {0.f,0.f,0.f,0.f};
      int n = nt*16 + lo;
#pragma unroll
      for (int ks = 0; ks < 2; ++ks) {
        bf16x8 bfv = *(const bf16x8*)(w2bf + n*64 + ks*32 + hi*8);
        acc0 = __builtin_amdgcn_mfma_f32_16x16x32_bf16(af[0][ks], bfv, acc0, 0, 0, 0);
        acc1 = __builtin_amdgcn_mfma_f32_16x16x32_bf16(af[1][ks], bfv, acc1, 0, 0, 0);
      }
      float sc = sc2[n], sh = sh2f[n];
#pragma unroll
      for (int mt = 0; mt < 2; ++mt) {
        f32x4 c = mt ? acc1 : acc0;
#pragma unroll
        for (int r = 0; r < 4; ++r) {
          int row = w*32 + mt*16 + hi*4 + r;
          unsigned short v = f2bf(fmaxf(c[r]*sc + sh, 0.f));
          *(short*)(lds + 16384 + row*256 + ((n*2) ^ ((row&7)<<4))) = (short)v;
        }
      }
    }
  }
  __syncthreads();

  // ---- P3 ----
  {
    bf16x8 af[2][4];
#pragma unroll
    for (int mt = 0; mt < 2; ++mt) {
      int row = w*32 + mt*16 + lo;
#pragma unroll
      for (int ks = 0; ks < 4; ++ks)
        af[mt][ks] = *(const bf16x8*)(lds + 16384 + row*256 + ((ks*64 + hi*16) ^ ((row&7)<<4)));
    }
    size_t gtask = (size_t)blockIdx.x*4 + w;
#pragma unroll 4
    for (int nt = 0; nt < 24; ++nt) {
      f32x4 acc0 = {0.f,0.f,0.f,0.f}, acc1 = {0.f,0.f,0.f,0.f};
      int e = nt*16 + lo;
#pragma unroll
      for (int ks = 0; ks < 4; ++ks) {
        bf16x8 bfv = *(const bf16x8*)(w3bf + e*128 + ks*32 + hi*8);
        acc0 = __builtin_amdgcn_mfma_f32_16x16x32_bf16(af[0][ks], bfv, acc0, 0, 0, 0);
        acc1 = __builtin_amdgcn_mfma_f32_16x16x32_bf16(af[1][ks], bfv, acc1, 0, 0, 0);
      }
      float m0 = fmaxf(fmaxf(acc0[0], acc0[1]), fmaxf(acc0[2], acc0[3]));
      float m1 = fmaxf(fmaxf(acc1[0], acc1[1]), fmaxf(acc1[2], acc1[3]));
      float m = fmaxf(m0, m1);
      m = fmaxf(m, __shfl_xor(m, 16, 64));
      m = fmaxf(m, __shfl_xor(m, 32, 64));
      if (l < 16) out[gtask*C3_ + e] = m + b3[e];
    }
  }
}

// ---------------------------------------------------------------------------
extern "C" void kernel_launch(void* const* d_in, const int* in_sizes, int n_in,
                              void* d_out, int out_size, void* d_ws, size_t ws_size,
                              hipStream_t stream) {
  (void)in_sizes; (void)n_in; (void)out_size; (void)ws_size;
  const float* x   = (const float*)d_in[0];
  const float* W1  = (const float*)d_in[1];
  const float* b1  = (const float*)d_in[2];
  const float* g1  = (const float*)d_in[3];
  const float* be1 = (const float*)d_in[4];
  const float* W2  = (const float*)d_in[5];
  const float* b2  = (const float*)d_in[6];
  const float* g2  = (const float*)d_in[7];
  const float* be2 = (const float*)d_in[8];
  const float* W3  = (const float*)d_in[9];
  const float* b3  = (const float*)d_in[10];
  float* out = (float*)d_out;
  float* ws  = (float*)d_ws;

  float* patches = ws + PATCH_OFF;
  float* centers = ws + CENT_OFF;
  float* part1   = ws + P1_OFF;
  float* sc1     = ws + SC1_OFF; float* sh1 = sc1 + C1_;
  float* part2   = ws + P2_OFF;
  float* sc2     = ws + SC2_OFF; float* sh2 = sc2 + C2_;
  short* w2bf    = (short*)(ws + W2BF_OFF);
  short* w3bf    = (short*)(ws + W3BF_OFF);
  float* outCent = out + (size_t)B_*S_*C3_;

  prep_kernel<<<dim3((C2_*C1_ + C3_*C2_)/256), dim3(256), 0, stream>>>(W2, W3, w2bf, w3bf);
  fps_kernel<<<dim3(B_), dim3(1024), 0, stream>>>(x, centers, outCent);
  qb_kernel<<<dim3(4096), dim3(256), 0, stream>>>(x, centers, patches);
  stats1_kernel<<<dim3(NB1_), dim3(256), 0, stream>>>(patches, W1, b1, part1);
  finalize_kernel<<<dim3(1), dim3(64), 0, stream>>>(part1, NB1_, C1_, g1, be1, nullptr, sc1, sh1);
  stats2_kernel<<<dim3(NB2_), dim3(256), 0, stream>>>(patches, W1, b1, sc1, sh1, W2, b2, part2);
  finalize_kernel<<<dim3(1), dim3(128), 0, stream>>>(part2, NB2_, C2_, g2, be2, b2, sc2, sh2);
  embed_kernel<<<dim3(1024), dim3(256), 0, stream>>>(patches, W1, b1, sc1, sh1,
                                                     w2bf, sc2, sh2, w3bf, b3, out);
}